// Round 1
// baseline (7003.944 us; speedup 1.0000x reference)
//
#include <hip/hip_runtime.h>
#include <math.h>

// Problem constants
#define BATCH 128
#define CIN   3
#define DIN   16
#define HWIN  64
#define COUT  24
#define DOUT  14   // 16 - 3 + 1
#define HOUT  62   // 64 - 3 + 1
#define WOUT  62

// x:    [128][3][16][64][64]  fp32
// w:    [24][3][3][3][3]      fp32  (co, cin, kd, kh, kw)
// bias: [24]
// out:  [128][24][62][62]     fp32 softmax over channel dim

__global__ __launch_bounds__(256, 1) void conv_min_softmax_kernel(
    const float* __restrict__ x,
    const float* __restrict__ w,
    const float* __restrict__ bias,
    float* __restrict__ out)
{
    const int idx = blockIdx.x * 256 + threadIdx.x;   // 0 .. 492031 (exact grid)
    const int wo = idx % WOUT;
    const int t  = idx / WOUT;
    const int ho = t % HOUT;
    const int b  = t / HOUT;

    const float* xb = x + (size_t)b * (CIN * DIN * HWIN * HWIN);

    // Rolling window of 3 depth planes; each plane: [cin][kh][kw] = 27 floats.
    float win[3][27];

    // Preload planes d=0,1 into slots 0,1
    #pragma unroll
    for (int kd = 0; kd < 2; ++kd) {
        #pragma unroll
        for (int cin = 0; cin < CIN; ++cin) {
            #pragma unroll
            for (int kh = 0; kh < 3; ++kh) {
                #pragma unroll
                for (int kw = 0; kw < 3; ++kw) {
                    win[kd][cin * 9 + kh * 3 + kw] =
                        xb[(cin * DIN + kd) * (HWIN * HWIN) + (ho + kh) * HWIN + (wo + kw)];
                }
            }
        }
    }

    float m[COUT];
    #pragma unroll
    for (int co = 0; co < COUT; ++co) m[co] = 1e30f;

    #pragma unroll 1   // keep the depth loop rolled: body is ~2k FMAs already
    for (int dz = 0; dz < DOUT; ++dz) {
        // Load plane dz+2 into slot 2 (27 coalesced loads)
        #pragma unroll
        for (int cin = 0; cin < CIN; ++cin) {
            #pragma unroll
            for (int kh = 0; kh < 3; ++kh) {
                #pragma unroll
                for (int kw = 0; kw < 3; ++kw) {
                    win[2][cin * 9 + kh * 3 + kw] =
                        xb[(cin * DIN + dz + 2) * (HWIN * HWIN) + (ho + kh) * HWIN + (wo + kw)];
                }
            }
        }

        // 24 channels x 81 taps; weight index is wave-uniform -> s_load
        #pragma unroll
        for (int co = 0; co < COUT; ++co) {
            float acc = 0.0f;
            #pragma unroll
            for (int cin = 0; cin < CIN; ++cin) {
                #pragma unroll
                for (int kd = 0; kd < 3; ++kd) {
                    #pragma unroll
                    for (int kh = 0; kh < 3; ++kh) {
                        #pragma unroll
                        for (int kw = 0; kw < 3; ++kw) {
                            acc = fmaf(w[co * 81 + cin * 27 + kd * 9 + kh * 3 + kw],
                                       win[kd][cin * 9 + kh * 3 + kw], acc);
                        }
                    }
                }
            }
            m[co] = fminf(m[co], acc);
        }

        // Rotate window (54 movs, ~3% of the 1944 FMAs above)
        #pragma unroll
        for (int q = 0; q < 27; ++q) { win[0][q] = win[1][q]; win[1][q] = win[2][q]; }
    }

    // bias (depth-invariant, so added after the min), then softmax over channels
    float mx = -1e30f;
    #pragma unroll
    for (int co = 0; co < COUT; ++co) {
        m[co] += bias[co];
        mx = fmaxf(mx, m[co]);
    }
    float s = 0.0f;
    #pragma unroll
    for (int co = 0; co < COUT; ++co) {
        m[co] = __expf(m[co] - mx);
        s += m[co];
    }
    const float inv = 1.0f / s;

    const size_t obase = ((size_t)b * COUT) * (HOUT * WOUT) + ho * WOUT + wo;
    #pragma unroll
    for (int co = 0; co < COUT; ++co) {
        out[obase + (size_t)co * (HOUT * WOUT)] = m[co] * inv;
    }
}

extern "C" void kernel_launch(void* const* d_in, const int* in_sizes, int n_in,
                              void* d_out, int out_size, void* d_ws, size_t ws_size,
                              hipStream_t stream) {
    const float* x    = (const float*)d_in[0];
    const float* w    = (const float*)d_in[1];
    const float* bias = (const float*)d_in[2];
    float* out = (float*)d_out;

    const int total = BATCH * HOUT * WOUT;           // 492032
    const int blocks = (total + 255) / 256;          // 1922 exactly
    conv_min_softmax_kernel<<<blocks, 256, 0, stream>>>(x, w, bias, out);
}

// Round 2
// 457.038 us; speedup vs baseline: 15.3246x; 15.3246x over previous
//
#include <hip/hip_runtime.h>
#include <math.h>

// Problem constants
#define BATCH 128
#define CIN   3
#define DIN   16
#define HWIN  64
#define COUT  24
#define DOUT  14   // 16 - 3 + 1
#define HOUT  62   // 64 - 3 + 1
#define WOUT  62

// x:    [128][3][16][64][64]  fp32
// w:    [24][3][3][3][3]      fp32  (co, cin, kd, kh, kw)
// bias: [24]
// out:  [128][24][62][62]     fp32 softmax over channel dim
//
// Block = 192 threads = 24 co x 8 pixel-groups; one (b, ho) output row per block.
// Each thread owns ONE output channel -> its 81 weights live in VGPRs, loaded once.
// x staged in LDS: rolling 3-plane window, each plane = 3 cin x 3 rows x 64 cols.

__global__ __launch_bounds__(192, 3) void conv_min_softmax_v2(
    const float* __restrict__ x,
    const float* __restrict__ w,
    const float* __restrict__ bias,
    float* __restrict__ out)
{
    // rows padded 64 -> 68: keeps 16B alignment (68%4==0) and allows the wg=7
    // strip to read 2 floats past col 63 without touching the next row's data.
    __shared__ __align__(16) float sx[3][9][68];   // [plane][cin*3+row][col]
    __shared__ float sm[COUT][64];                 // per-row channel mins for softmax

    const int tid = threadIdx.x;
    const int bid = blockIdx.x;          // 0 .. 128*62-1
    const int ho  = bid % HOUT;
    const int b   = bid / HOUT;

    const int co = tid >> 3;             // 0..23
    const int wg = tid & 7;              // 0..7 -> pixels wo = wg*8 .. wg*8+7

    const float* xb = x + (size_t)b * (CIN * DIN * HWIN * HWIN);

    // ---- weights for this thread's channel: 81 VGPRs, loaded once ----
    float wreg[81];
    #pragma unroll
    for (int q = 0; q < 81; ++q) wreg[q] = w[co * 81 + q];
    const float bco = bias[co];

    // staging decomposition: each thread loads 3 elements (one per cin)
    const int r  = tid >> 6;             // 0..2 input row within plane
    const int wc = tid & 63;             // 0..63 col

    // preload depth planes 0,1 into slots 0,1
    #pragma unroll
    for (int d = 0; d < 2; ++d) {
        #pragma unroll
        for (int cin = 0; cin < CIN; ++cin) {
            sx[d][cin * 3 + r][wc] =
                xb[(cin * DIN + d) * (HWIN * HWIN) + (ho + r) * HWIN + wc];
        }
    }

    float m[8];
    #pragma unroll
    for (int i = 0; i < 8; ++i) m[i] = 1e30f;

    #pragma unroll 1
    for (int dz = 0; dz < DOUT; ++dz) {
        // stage plane d = dz+2 into slot (dz+2)%3  (3 coalesced row loads/thread)
        const int s2 = (dz + 2) % 3;
        #pragma unroll
        for (int cin = 0; cin < CIN; ++cin) {
            sx[s2][cin * 3 + r][wc] =
                xb[(cin * DIN + dz + 2) * (HWIN * HWIN) + (ho + r) * HWIN + wc];
        }
        __syncthreads();

        const int p0 = dz % 3;
        const int p1 = (dz + 1) % 3;
        // plane slots for kd = 0,1,2
        const float* planes[3] = { &sx[p0][0][0], &sx[p1][0][0], &sx[s2][0][0] };

        float acc[8];
        #pragma unroll
        for (int i = 0; i < 8; ++i) acc[i] = 0.f;

        #pragma unroll
        for (int kd = 0; kd < 3; ++kd) {
            const float* plane = planes[kd];
            #pragma unroll
            for (int cin = 0; cin < CIN; ++cin) {
                #pragma unroll
                for (int kh = 0; kh < 3; ++kh) {
                    const float* rp = plane + (cin * 3 + kh) * 68 + wg * 8;
                    float xr[10];
                    const float4 q0 = *(const float4*)(rp);
                    const float4 q1 = *(const float4*)(rp + 4);
                    const float2 q2 = *(const float2*)(rp + 8);
                    xr[0] = q0.x; xr[1] = q0.y; xr[2] = q0.z; xr[3] = q0.w;
                    xr[4] = q1.x; xr[5] = q1.y; xr[6] = q1.z; xr[7] = q1.w;
                    xr[8] = q2.x; xr[9] = q2.y;
                    #pragma unroll
                    for (int kw = 0; kw < 3; ++kw) {
                        const float wv = wreg[cin * 27 + kd * 9 + kh * 3 + kw];
                        #pragma unroll
                        for (int i = 0; i < 8; ++i)
                            acc[i] = fmaf(wv, xr[i + kw], acc[i]);
                    }
                }
            }
        }
        #pragma unroll
        for (int i = 0; i < 8; ++i) m[i] = fminf(m[i], acc[i]);
        __syncthreads();   // protect slot p0 from next iteration's staging write
    }

    // ---- epilogue: bias, then per-pixel softmax across the 24 channels ----
    #pragma unroll
    for (int i = 0; i < 8; ++i) sm[co][wg * 8 + i] = m[i] + bco;  // cols 62,63 unused
    __syncthreads();

    if (tid < WOUT) {
        const int p = tid;
        float mx = -1e30f;
        #pragma unroll
        for (int c = 0; c < COUT; ++c) mx = fmaxf(mx, sm[c][p]);
        float e[COUT];
        float ssum = 0.f;
        #pragma unroll
        for (int c = 0; c < COUT; ++c) { e[c] = __expf(sm[c][p] - mx); ssum += e[c]; }
        const float inv = 1.f / ssum;
        float* ob = out + (size_t)b * COUT * (HOUT * WOUT) + ho * WOUT + p;
        #pragma unroll
        for (int c = 0; c < COUT; ++c) ob[(size_t)c * (HOUT * WOUT)] = e[c] * inv;
    }
}

extern "C" void kernel_launch(void* const* d_in, const int* in_sizes, int n_in,
                              void* d_out, int out_size, void* d_ws, size_t ws_size,
                              hipStream_t stream) {
    const float* x    = (const float*)d_in[0];
    const float* w    = (const float*)d_in[1];
    const float* bias = (const float*)d_in[2];
    float* out = (float*)d_out;

    const int blocks = BATCH * HOUT;     // 7936
    conv_min_softmax_v2<<<blocks, 192, 0, stream>>>(x, w, bias, out);
}